// Round 10
// baseline (48.227 us; speedup 1.0000x reference)
//
#include <hip/hip_runtime.h>
#include <hip/hip_fp16.h>
#include <math.h>

constexpr int D    = 1024;
constexpr int NEXP = 4;
constexpr int EPP  = 2048;

typedef _Float16 f16x8 __attribute__((ext_vector_type(8)));
typedef float    f32x4 __attribute__((ext_vector_type(4)));

__device__ __forceinline__ unsigned pk2(float a, float b) {
    return __builtin_bit_cast(unsigned, __builtin_amdgcn_cvt_pkrtz(a, b));
}

// ---------------- K1: prep (blocks 0..63) + router (blocks 64..) ----------------
__global__ __launch_bounds__(256) void prep_router_kernel(
    const float* __restrict__ h, const float* __restrict__ lts,
    const float* __restrict__ Wr, const float* __restrict__ br,
    float* __restrict__ out_ew, int* __restrict__ eidx,
    _Float16* __restrict__ h16, _Float16* __restrict__ lts16,
    _Float16* __restrict__ ltsT, int ntok)
{
    const int tid = threadIdx.x;

    if (blockIdx.x < 64) {
        // ---- prep: f16 slice copies ----
        const int e = blockIdx.x >> 4, part = (blockIdx.x >> 2) & 3, dc = blockIdx.x & 3;
        __shared__ __align__(16) _Float16 s[8][256];

        const float4* src = reinterpret_cast<const float4*>(lts);
        #pragma unroll
        for (int i = 0; i < 2; ++i) {
            const int f = tid + 256 * i;
            const int r = f >> 6, c4 = f & 63;
            const float4 v = src[(size_t)(e * EPP + part * 8 + r) * 256 + dc * 64 + c4];
            *reinterpret_cast<uint2*>(&s[r][c4 * 4]) = make_uint2(pk2(v.x, v.y), pk2(v.z, v.w));
        }
        __syncthreads();

        {   // row-major copy
            const int r = tid >> 5, c = tid & 31;
            *reinterpret_cast<uint4*>(lts16 + (size_t)(e * 32 + part * 8 + r) * D + dc * 256 + c * 8) =
                *reinterpret_cast<const uint4*>(&s[r][c * 8]);
        }
        {   // transposed copy
            _Float16 tmp[8];
            #pragma unroll
            for (int k = 0; k < 8; ++k) tmp[k] = s[k][tid];
            *reinterpret_cast<uint4*>(ltsT + ((size_t)e << 15) + (size_t)(dc * 256 + tid) * 32 + part * 8) =
                *reinterpret_cast<const uint4*>(tmp);
        }
        return;
    }

    // ---- router: 1 token per wave ----
    const int wid = tid >> 6, lane = tid & 63;
    const int tok = (blockIdx.x - 64) * 4 + wid;
    if (tok >= ntok) return;

    const float4* h4 = reinterpret_cast<const float4*>(h);
    const float4* w4 = reinterpret_cast<const float4*>(Wr);

    float4 av[4];
    float acc[NEXP] = {0.f, 0.f, 0.f, 0.f};
    #pragma unroll
    for (int i = 0; i < 4; ++i) {
        av[i] = h4[(size_t)tok * 256 + lane + 64 * i];
        #pragma unroll
        for (int e = 0; e < NEXP; ++e) {
            const float4 w = w4[e * 256 + lane + 64 * i];
            acc[e] += av[i].x * w.x + av[i].y * w.y + av[i].z * w.z + av[i].w * w.w;
        }
    }
    #pragma unroll
    for (int m = 1; m < 64; m <<= 1)
        #pragma unroll
        for (int e = 0; e < NEXP; ++e) acc[e] += __shfl_xor(acc[e], m);

    const float l0 = acc[0] + br[0], l1 = acc[1] + br[1],
                l2 = acc[2] + br[2], l3 = acc[3] + br[3];
    const float lm = fmaxf(fmaxf(l0, l1), fmaxf(l2, l3));
    const float e0 = __expf(l0 - lm), e1 = __expf(l1 - lm),
                e2 = __expf(l2 - lm), e3 = __expf(l3 - lm);
    const float einv = 1.f / (e0 + e1 + e2 + e3);
    if (lane < NEXP) {
        const float ev = (lane == 0) ? e0 : (lane == 1) ? e1 : (lane == 2) ? e2 : e3;
        out_ew[(size_t)tok * NEXP + lane] = ev * einv;
    }
    int bi = 0; float bv = l0;
    if (l1 > bv) { bv = l1; bi = 1; }
    if (l2 > bv) { bv = l2; bi = 2; }
    if (l3 > bv) { bv = l3; bi = 3; }
    if (lane == 0) eidx[tok] = bi;

    #pragma unroll
    for (int i = 0; i < 4; ++i)
        *reinterpret_cast<uint2*>(h16 + (size_t)tok * D + (lane + 64 * i) * 4) =
            make_uint2(pk2(av[i].x, av[i].y), pk2(av[i].z, av[i].w));
}

// ---------------- K2: fused QK + softmax + PV, 8 tokens/block ----------------
// QK: all 4 experts, K-split by wave (kc in [wid*8,wid*8+8)), partials in LDS.
// Softmax: 32 threads per token over its routed expert's 32 scores.
// PV: one-hot P(8x128) x V(128x1024); wave owns 256 dims.
__global__ __launch_bounds__(256) void attn_kernel(
    const _Float16* __restrict__ h16, const _Float16* __restrict__ lts16,
    const _Float16* __restrict__ ltsT, const int* __restrict__ eidx,
    float* __restrict__ out_res, int ntok)
{
    const int tid = threadIdx.x, wid = tid >> 6, lane = tid & 63;
    const int base = blockIdx.x * 8;

    __shared__ int eix[8];
    __shared__ float S[4][8][130];                       // 16.6 KB padded
    __shared__ __align__(16) unsigned char p_lds[8 * 256];

    if (tid < 8) {
        const int tk = base + tid;
        eix[tid] = (tk < ntok) ? eidx[tk] : 0;
    }
    if (tid < 128) *reinterpret_cast<uint4*>(p_lds + tid * 16) = make_uint4(0, 0, 0, 0);

    const int rA = lane & 15, g4 = lane >> 4;
    const int arow = rA & 7;                             // token row (8..15 dup)
    int htok = base + arow; if (htok > ntok - 1) htok = ntok - 1;
    const _Float16* ap = h16 + (size_t)htok * D + g4 * 8;

    // ---- QK: 8 col-tiles (4 experts x 2), 8 kc per wave ----
    f32x4 s[8];
    #pragma unroll
    for (int ct = 0; ct < 8; ++ct) s[ct] = (f32x4){0.f, 0.f, 0.f, 0.f};
    #pragma unroll
    for (int k = 0; k < 8; ++k) {
        const int kc = wid * 8 + k;
        const f16x8 a = *reinterpret_cast<const f16x8*>(ap + kc * 32);
        #pragma unroll
        for (int ct = 0; ct < 8; ++ct) {
            const f16x8 b = *reinterpret_cast<const f16x8*>(
                lts16 + (size_t)(ct * 16 + rA) * D + kc * 32 + g4 * 8);
            s[ct] = __builtin_amdgcn_mfma_f32_16x16x32_f16(a, b, s[ct], 0, 0, 0);
        }
    }
    #pragma unroll
    for (int ct = 0; ct < 8; ++ct)
        #pragma unroll
        for (int r = 0; r < 4; ++r) {
            const int tr = g4 * 4 + r;
            if (tr < 8) S[wid][tr][ct * 16 + rA] = s[ct][r];
        }
    __syncthreads();

    // ---- reduce + softmax: thread -> (token tr, score col sl) ----
    {
        const int tr = tid >> 5, sl = tid & 31;
        const int col = eix[tr] * 32 + sl;
        const float v = S[0][tr][col] + S[1][tr][col] + S[2][tr][col] + S[3][tr][col];
        constexpr float inv32 = 1.f / 32.f;              // 1/sqrt(1024)
        float mx = v;
        #pragma unroll
        for (int m = 1; m < 32; m <<= 1) mx = fmaxf(mx, __shfl_xor(mx, m));
        const float p = __expf((v - mx) * inv32);
        float sm = p;
        #pragma unroll
        for (int m = 1; m < 32; m <<= 1) sm += __shfl_xor(sm, m);
        const float pn = p / sm;
        const int g = col >> 3;                          // 16B granule 0..15
        *reinterpret_cast<_Float16*>(p_lds + tr * 256 + ((g ^ tr) << 4) + (col & 7) * 2) =
            (_Float16)pn;
    }
    __syncthreads();

    // ---- PV ----
    f16x8 pa[4];
    #pragma unroll
    for (int kc = 0; kc < 4; ++kc)
        pa[kc] = *reinterpret_cast<const f16x8*>(
            p_lds + arow * 256 + ((((kc << 2) | g4) ^ arow) << 4));

    #pragma unroll
    for (int i = 0; i < 16; ++i) {
        const int dimc = wid * 256 + i * 16 + rA;
        f32x4 o = {0.f, 0.f, 0.f, 0.f};
        #pragma unroll
        for (int kc = 0; kc < 4; ++kc) {
            const f16x8 bk = *reinterpret_cast<const f16x8*>(
                ltsT + ((size_t)kc << 15) + (size_t)dimc * 32 + g4 * 8);
            o = __builtin_amdgcn_mfma_f32_16x16x32_f16(pa[kc], bk, o, 0, 0, 0);
        }
        #pragma unroll
        for (int r = 0; r < 4; ++r) {
            const int tr2 = g4 * 4 + r;
            if (tr2 < 8 && base + tr2 < ntok)
                out_res[(size_t)(base + tr2) * D + dimc] = o[r];
        }
    }
}

extern "C" void kernel_launch(void* const* d_in, const int* in_sizes, int n_in,
                              void* d_out, int out_size, void* d_ws, size_t ws_size,
                              hipStream_t stream) {
    const float* h   = (const float*)d_in[0];
    const float* lts = (const float*)d_in[1];
    const float* Wr  = (const float*)d_in[2];
    const float* br  = (const float*)d_in[3];

    const int ntok = in_sizes[0] / D;            // b*t = 4096
    float* out_res = (float*)d_out;              // (b,t,d)
    float* out_ew  = out_res + (size_t)ntok * D; // (b,t,NEXP)

    _Float16* lts16 = (_Float16*)d_ws;                    // 128x1024 (256 KB)
    _Float16* ltsT  = lts16 + (size_t)128 * D;            // 4x1024x32 (256 KB)
    int*      eidx  = (int*)(ltsT + (size_t)NEXP * D * 32);
    _Float16* h16   = (_Float16*)(eidx + ntok);           // ntok x 1024 (8 MB)

    const int rblocks = 64 + (ntok + 3) / 4;     // 64 prep + 1024 router
    prep_router_kernel<<<rblocks, 256, 0, stream>>>(h, lts, Wr, br, out_ew, eidx,
                                                    h16, lts16, ltsT, ntok);
    attn_kernel<<<(ntok + 7) / 8, 256, 0, stream>>>(h16, lts16, ltsT, eidx,
                                                    out_res, ntok);
}

// Round 11
// 35.640 us; speedup vs baseline: 1.3532x; 1.3532x over previous
//
#include <hip/hip_runtime.h>
#include <hip/hip_fp16.h>
#include <math.h>

constexpr int D    = 1024;
constexpr int NEXP = 4;
constexpr int EPP  = 2048;

typedef _Float16 f16x8 __attribute__((ext_vector_type(8)));
typedef float    f32x4 __attribute__((ext_vector_type(4)));

__device__ __forceinline__ unsigned pk2(float a, float b) {
    return __builtin_bit_cast(unsigned, __builtin_amdgcn_cvt_pkrtz(a, b));
}

// ---------------- K1: prep (blocks 0..63) + router (blocks 64..) ----------------
__global__ __launch_bounds__(256) void prep_router_kernel(
    const float* __restrict__ h, const float* __restrict__ lts,
    const float* __restrict__ Wr, const float* __restrict__ br,
    float* __restrict__ out_ew, int* __restrict__ eidx,
    _Float16* __restrict__ h16, _Float16* __restrict__ lts16,
    _Float16* __restrict__ ltsT, int ntok)
{
    const int tid = threadIdx.x;

    if (blockIdx.x < 64) {
        // ---- prep: f16 slice copies ----
        const int e = blockIdx.x >> 4, part = (blockIdx.x >> 2) & 3, dc = blockIdx.x & 3;
        __shared__ __align__(16) _Float16 s[8][256];

        const float4* src = reinterpret_cast<const float4*>(lts);
        #pragma unroll
        for (int i = 0; i < 2; ++i) {
            const int f = tid + 256 * i;
            const int r = f >> 6, c4 = f & 63;
            const float4 v = src[(size_t)(e * EPP + part * 8 + r) * 256 + dc * 64 + c4];
            *reinterpret_cast<uint2*>(&s[r][c4 * 4]) = make_uint2(pk2(v.x, v.y), pk2(v.z, v.w));
        }
        __syncthreads();

        {   // row-major copy
            const int r = tid >> 5, c = tid & 31;
            *reinterpret_cast<uint4*>(lts16 + (size_t)(e * 32 + part * 8 + r) * D + dc * 256 + c * 8) =
                *reinterpret_cast<const uint4*>(&s[r][c * 8]);
        }
        {   // transposed copy
            _Float16 tmp[8];
            #pragma unroll
            for (int k = 0; k < 8; ++k) tmp[k] = s[k][tid];
            *reinterpret_cast<uint4*>(ltsT + ((size_t)e << 15) + (size_t)(dc * 256 + tid) * 32 + part * 8) =
                *reinterpret_cast<const uint4*>(tmp);
        }
        return;
    }

    // ---- router: 1 token per wave ----
    const int wid = tid >> 6, lane = tid & 63;
    const int tok = (blockIdx.x - 64) * 4 + wid;
    if (tok >= ntok) return;

    const float4* h4 = reinterpret_cast<const float4*>(h);
    const float4* w4 = reinterpret_cast<const float4*>(Wr);

    float4 av[4];
    float acc[NEXP] = {0.f, 0.f, 0.f, 0.f};
    #pragma unroll
    for (int i = 0; i < 4; ++i) {
        av[i] = h4[(size_t)tok * 256 + lane + 64 * i];
        #pragma unroll
        for (int e = 0; e < NEXP; ++e) {
            const float4 w = w4[e * 256 + lane + 64 * i];
            acc[e] += av[i].x * w.x + av[i].y * w.y + av[i].z * w.z + av[i].w * w.w;
        }
    }
    #pragma unroll
    for (int m = 1; m < 64; m <<= 1)
        #pragma unroll
        for (int e = 0; e < NEXP; ++e) acc[e] += __shfl_xor(acc[e], m);

    const float l0 = acc[0] + br[0], l1 = acc[1] + br[1],
                l2 = acc[2] + br[2], l3 = acc[3] + br[3];
    const float lm = fmaxf(fmaxf(l0, l1), fmaxf(l2, l3));
    const float e0 = __expf(l0 - lm), e1 = __expf(l1 - lm),
                e2 = __expf(l2 - lm), e3 = __expf(l3 - lm);
    const float einv = 1.f / (e0 + e1 + e2 + e3);
    if (lane < NEXP) {
        const float ev = (lane == 0) ? e0 : (lane == 1) ? e1 : (lane == 2) ? e2 : e3;
        out_ew[(size_t)tok * NEXP + lane] = ev * einv;
    }
    int bi = 0; float bv = l0;
    if (l1 > bv) { bv = l1; bi = 1; }
    if (l2 > bv) { bv = l2; bi = 2; }
    if (l3 > bv) { bv = l3; bi = 3; }
    if (lane == 0) eidx[tok] = bi;

    #pragma unroll
    for (int i = 0; i < 4; ++i)
        *reinterpret_cast<uint2*>(h16 + (size_t)tok * D + (lane + 64 * i) * 4) =
            make_uint2(pk2(av[i].x, av[i].y), pk2(av[i].z, av[i].w));
}

// ---------------- K2: qk + softmax + pv for one (expert, 16-token chunk) ----------------
// QK: S(16x32) = H16 . K_e^T, K-split across 4 waves (8 kc each), LDS reduce.
// Softmax: 16 threads/token (2 cols each).
// PV: O(16x1024) = P(16x32) . V_e(32x1024) -- 64 N-tiles, 1 MFMA each, 16/wave.
// Token outputs written only by the block whose e == eidx[token].
__global__ __launch_bounds__(256) void qkpv_kernel(
    const _Float16* __restrict__ h16, const _Float16* __restrict__ lts16,
    const _Float16* __restrict__ ltsT, const int* __restrict__ eidx,
    float* __restrict__ out_res, int ntok, int chunks)
{
    const int e = blockIdx.x / chunks;
    const int chunk = blockIdx.x - e * chunks;
    const int base = chunk * 16;

    const int tid = threadIdx.x, wid = tid >> 6, lane = tid & 63;
    __shared__ int eix[16];
    __shared__ float S_part[4][16][33];                  // 8.25 KB
    __shared__ __align__(16) _Float16 P[16][32];         // 1 KB

    if (tid < 16) {
        const int tk = base + tid;
        eix[tid] = (tk < ntok) ? eidx[tk] : -1;
    }

    const int rA = lane & 15, g4 = lane >> 4;
    int hr = base + rA; if (hr > ntok - 1) hr = ntok - 1;
    const _Float16* ap  = h16   + (size_t)hr * D + g4 * 8;
    const _Float16* b0p = lts16 + (size_t)(e * 32 + rA) * D + g4 * 8;
    const _Float16* b1p = b0p + 16 * D;

    // ---- QK: wave wid covers kc in [wid*8, wid*8+8) ----
    f32x4 s0 = {0.f, 0.f, 0.f, 0.f}, s1 = {0.f, 0.f, 0.f, 0.f};
    #pragma unroll
    for (int k = 0; k < 8; ++k) {
        const int kc = wid * 8 + k;
        const f16x8 a  = *reinterpret_cast<const f16x8*>(ap  + kc * 32);
        const f16x8 b0 = *reinterpret_cast<const f16x8*>(b0p + kc * 32);
        const f16x8 b1 = *reinterpret_cast<const f16x8*>(b1p + kc * 32);
        s0 = __builtin_amdgcn_mfma_f32_16x16x32_f16(a, b0, s0, 0, 0, 0);
        s1 = __builtin_amdgcn_mfma_f32_16x16x32_f16(a, b1, s1, 0, 0, 0);
    }
    #pragma unroll
    for (int r = 0; r < 4; ++r) {
        S_part[wid][g4 * 4 + r][rA]      = s0[r];
        S_part[wid][g4 * 4 + r][rA + 16] = s1[r];
    }
    __syncthreads();

    // ---- reduce + softmax: thread -> (token tr, cols sl & sl+16) ----
    {
        const int tr = tid >> 4, sl = tid & 15;
        const float v0 = S_part[0][tr][sl] + S_part[1][tr][sl]
                       + S_part[2][tr][sl] + S_part[3][tr][sl];
        const float v1 = S_part[0][tr][sl + 16] + S_part[1][tr][sl + 16]
                       + S_part[2][tr][sl + 16] + S_part[3][tr][sl + 16];
        constexpr float inv32 = 1.f / 32.f;              // 1/sqrt(1024)
        float mx = fmaxf(v0, v1);
        #pragma unroll
        for (int m = 1; m < 16; m <<= 1) mx = fmaxf(mx, __shfl_xor(mx, m));
        const float p0 = __expf((v0 - mx) * inv32);
        const float p1 = __expf((v1 - mx) * inv32);
        float sm = p0 + p1;
        #pragma unroll
        for (int m = 1; m < 16; m <<= 1) sm += __shfl_xor(sm, m);
        const float is = 1.f / sm;
        P[tr][sl]      = (_Float16)(p0 * is);
        P[tr][sl + 16] = (_Float16)(p1 * is);
    }
    __syncthreads();

    // ---- PV: wave wid owns dims [wid*256, wid*256+256) ----
    const f16x8 pa = *reinterpret_cast<const f16x8*>(&P[rA][g4 * 8]);
    const _Float16* vtE = ltsT + ((size_t)e << 15);

    #pragma unroll
    for (int i = 0; i < 16; ++i) {
        const int dimc = wid * 256 + i * 16 + rA;
        const f16x8 bk = *reinterpret_cast<const f16x8*>(vtE + (size_t)dimc * 32 + g4 * 8);
        f32x4 o = {0.f, 0.f, 0.f, 0.f};
        o = __builtin_amdgcn_mfma_f32_16x16x32_f16(pa, bk, o, 0, 0, 0);
        #pragma unroll
        for (int r = 0; r < 4; ++r) {
            const int tr2 = g4 * 4 + r;
            if (base + tr2 < ntok && eix[tr2] == e)
                out_res[(size_t)(base + tr2) * D + dimc] = o[r];
        }
    }
}

extern "C" void kernel_launch(void* const* d_in, const int* in_sizes, int n_in,
                              void* d_out, int out_size, void* d_ws, size_t ws_size,
                              hipStream_t stream) {
    const float* h   = (const float*)d_in[0];
    const float* lts = (const float*)d_in[1];
    const float* Wr  = (const float*)d_in[2];
    const float* br  = (const float*)d_in[3];

    const int ntok = in_sizes[0] / D;            // b*t = 4096
    float* out_res = (float*)d_out;              // (b,t,d)
    float* out_ew  = out_res + (size_t)ntok * D; // (b,t,NEXP)

    _Float16* lts16 = (_Float16*)d_ws;                    // 128x1024 (256 KB)
    _Float16* ltsT  = lts16 + (size_t)128 * D;            // 4x1024x32 (256 KB)
    int*      eidx  = (int*)(ltsT + (size_t)NEXP * D * 32);
    _Float16* h16   = (_Float16*)(eidx + ntok);           // ntok x 1024 (8 MB)

    const int chunks = (ntok + 15) / 16;         // 256

    const int rblocks = 64 + (ntok + 3) / 4;     // 64 prep + 1024 router
    prep_router_kernel<<<rblocks, 256, 0, stream>>>(h, lts, Wr, br, out_ew, eidx,
                                                    h16, lts16, ltsT, ntok);
    qkpv_kernel<<<NEXP * chunks, 256, 0, stream>>>(h16, lts16, ltsT, eidx,
                                                   out_res, ntok, chunks);
}